// Round 9
// baseline (314.530 us; speedup 1.0000x reference)
//
#include <hip/hip_runtime.h>
#include <hip/hip_fp16.h>
#include <cstddef>

#define Bc   32
#define Nc   512
#define Mc   512
#define DFc  64
#define BIGC 1.0e10f
#define LOG2E_F 1.4426950408889634f
#define LN2_F   0.6931471805599453f
#define SQRT_LOG2E_F 1.2011224087864498f

typedef unsigned int uint32;

__device__ __forceinline__ float dpp_shr1(float oldv, float src) {
    return __int_as_float(__builtin_amdgcn_update_dpp(
        __float_as_int(oldv), __float_as_int(src), 0x138, 0xf, 0xf, false));
}
__device__ __forceinline__ float dpp_shr1_nc(float src) {
    return __int_as_float(__builtin_amdgcn_mov_dpp(
        __float_as_int(src), 0x138, 0xf, 0xf, false));
}
__device__ __forceinline__ float rl(float v, int lane) {
    return __int_as_float(__builtin_amdgcn_readlane(__float_as_int(v), lane));
}

// Bit-trick softmin, log2 domain, minus 127 (bias pre-folded into Dsk).
// NOTE: no explicit clamp — v_cvt_u32_f32 saturates negative inputs to 0,
// which is exactly the fp-underflow behavior the clamp provided.
__device__ __forceinline__ float softmin3m(float a, float b, float c) {
    float mn = fminf(fminf(a, b), c);
    float mx = fmaxf(fmaxf(a, b), c);
    float md = __builtin_amdgcn_fmed3f(a, b, c);
    uint32 b1 = (uint32)fmaf(mn - mx, 8388608.0f, 1065353216.0f);
    uint32 b2 = (uint32)fmaf(mn - md, 8388608.0f, 1065353216.0f);
    float E = 1.0f + (__int_as_float(b1) + __int_as_float(b2));
    return fmaf((float)__float_as_uint(E), -1.1920929e-7f, mn);
}

// ---------------------------------------------------------------------------
// Kernel 1 (unchanged from r8): scaled (x LOG2E, +127) fp16 distances,
// skewed dwordx4 layout for the 2-col superstep scan.
// ---------------------------------------------------------------------------
__global__ __launch_bounds__(256) void dist_kernel(
    const float* __restrict__ X, const float* __restrict__ Y,
    uint32* __restrict__ Dsk)
{
    __shared__ __align__(16) unsigned char SMEM[34816];
    unsigned short* XsH = (unsigned short*)SMEM;
    unsigned short* YsH = (unsigned short*)(SMEM + 16384);
    uint32* P = (uint32*)SMEM;

    const int b     = blockIdx.z;
    const int strip = blockIdx.y;
    const int J     = blockIdx.x;
    const int tid   = threadIdx.x;

    const float* Xg = X + ((size_t)b * Nc + strip * 128) * DFc;
    const float* Yg = Y + ((size_t)b * Mc + J * 128) * DFc;

#pragma unroll
    for (int it = 0; it < 8; ++it) {
        int e4 = it * 256 + tid;
        int n = e4 >> 4, k4 = (e4 & 15) * 4;
        float4 v = ((const float4*)Xg)[e4];
        __half2 h01 = __floats2half2_rn(v.x * SQRT_LOG2E_F, v.y * SQRT_LOG2E_F);
        __half2 h23 = __floats2half2_rn(v.z * SQRT_LOG2E_F, v.w * SQRT_LOG2E_F);
        int ho = (k4 + 8 * ((n >> 3) & 7)) & 63;
        uint2 u; u.x = *(uint32*)&h01; u.y = *(uint32*)&h23;
        *(uint2*)&XsH[n * 64 + ho] = u;
    }
#pragma unroll
    for (int it = 0; it < 8; ++it) {
        int e4 = it * 256 + tid;
        int m = e4 >> 4, k4 = (e4 & 15) * 4;
        float4 v = ((const float4*)Yg)[e4];
        __half2 h01 = __floats2half2_rn(v.x * SQRT_LOG2E_F, v.y * SQRT_LOG2E_F);
        __half2 h23 = __floats2half2_rn(v.z * SQRT_LOG2E_F, v.w * SQRT_LOG2E_F);
        int ho = (k4 + 8 * ((m >> 3) & 7)) & 63;
        uint2 u; u.x = *(uint32*)&h01; u.y = *(uint32*)&h23;
        *(uint2*)&YsH[m * 64 + ho] = u;
    }
    __syncthreads();

    const int tx = tid & 15;
    const int ty = tid >> 4;

    __half2 acc[8][8];
#pragma unroll
    for (int a = 0; a < 8; ++a)
#pragma unroll
        for (int c = 0; c < 8; ++c) acc[a][c] = __floats2half2_rn(0.f, 0.f);

    const int xrot = 8 * (ty & 7);
    const int yrot = 8 * (tx & 7);

#pragma unroll 2
    for (int k8 = 0; k8 < 8; ++k8) {
        uint4 xv[8], yvv[8];
#pragma unroll
        for (int a = 0; a < 8; ++a)
            xv[a] = *(const uint4*)&XsH[(8 * ty + a) * 64 + ((k8 * 8 + xrot) & 63)];
#pragma unroll
        for (int c = 0; c < 8; ++c)
            yvv[c] = *(const uint4*)&YsH[(8 * tx + c) * 64 + ((k8 * 8 + yrot) & 63)];
#pragma unroll
        for (int a = 0; a < 8; ++a) {
            const uint32 xa[4] = {xv[a].x, xv[a].y, xv[a].z, xv[a].w};
#pragma unroll
            for (int c = 0; c < 8; ++c) {
                const uint32 ya[4] = {yvv[c].x, yvv[c].y, yvv[c].z, yvv[c].w};
#pragma unroll
                for (int t = 0; t < 4; ++t) {
                    __half2 xd = *(const __half2*)&xa[t];
                    __half2 yd = *(const __half2*)&ya[t];
                    __half2 d = __hsub2(xd, yd);
                    acc[a][c] = __hfma2(d, d, acc[a][c]);
                }
            }
        }
    }
    __syncthreads();

#pragma unroll
    for (int a = 0; a < 8; a += 2) {
        int p = 4 * ty + (a >> 1);
#pragma unroll
        for (int c = 0; c < 8; ++c) {
            float2 fa = __half22float2(acc[a][c]);
            float2 fb = __half22float2(acc[a + 1][c]);
            __half2 h = __floats2half2_rn(fa.x + fa.y + 127.0f,
                                          fb.x + fb.y + 127.0f);
            P[(8 * tx + c) * 67 + p] = *(uint32*)&h;
        }
    }
    __syncthreads();

    const int l = tid & 63;
    const int q = tid >> 6;
    uint4* outt = (uint4*)Dsk + (((size_t)b * 4 + strip) * 4 + J) * 4096;
    const uint32* Pl = P + l;
#pragma unroll
    for (int gi = 0; gi < 16; ++gi) {
        int g = q + 4 * gi;
        int ka = 4 * g - 2 * l;
        int c0 = min(max(ka,     0), 127);
        int c1 = min(max(ka + 1, 0), 127);
        int c2 = min(max(ka + 2, 0), 127);
        int c3 = min(max(ka + 3, 0), 127);
        uint32 p0 = Pl[c0 * 67];
        uint32 p1 = Pl[c1 * 67];
        uint32 p2 = Pl[c2 * 67];
        uint32 p3 = Pl[c3 * 67];
        uint4 v;
        v.x = (p0 & 0xffffu) | (p1 << 16);
        v.y = (p0 >> 16)     | (p1 & 0xffff0000u);
        v.z = (p2 & 0xffffu) | (p3 << 16);
        v.w = (p2 >> 16)     | (p3 & 0xffff0000u);
        outt[g * 64 + l] = v;
    }
}

// ---------------------------------------------------------------------------
// Kernel 2: DUAL-PIPELINE tile-systolic scan. 2 waves x 128-col superstep
// tiles; wave u interleaves strips u and u+2 (independent tiles within a
// barrier period) cell-by-cell -> dependent ops spaced by sibling-pipeline
// instructions (~2 cyc/inst instead of ~4.9 solo). Inactive pipelines run
// as held no-ops: act forced false (+256 lane bias), writes to dump; the
// diagA = dpp(held curB) recurrence reproduces the correct seed invariantly.
// ---------------------------------------------------------------------------
#define SS2(T, dA0, dB0, dA1, dB1, PH1)                                      \
  {                                                                          \
    float2 fA0 = __half22float2(*(const __half2*)&(dA0));                    \
    float2 fA1 = __half22float2(*(const __half2*)&(dA1));                    \
    float2 fB0 = __half22float2(*(const __half2*)&(dB0));                    \
    float2 fB1 = __half22float2(*(const __half2*)&(dB1));                    \
    float u10, u20, u11, u21;                                                \
    if (PH1) {                                                               \
      u10 = dpp_shr1(rl(Fodd0, (T) - 1), pub10);                             \
      u11 = dpp_shr1(rl(Fodd1, (T) - 1), pub11);                             \
      u20 = dpp_shr1(rl(Fev0,  (T) - 1), curB0);                             \
      u21 = dpp_shr1(rl(Fev1,  (T) - 1), curB1);                             \
    } else {                                                                 \
      u10 = dpp_shr1_nc(pub10);  u11 = dpp_shr1_nc(pub11);                   \
      u20 = dpp_shr1_nc(curB0);  u21 = dpp_shr1_nc(curB1);                   \
    }                                                                        \
    float A10 = softmin3m(diagA0, u10, curA0) + fA0.x;                       \
    float A11 = softmin3m(diagA1, u11, curA1) + fA1.x;                       \
    float A20 = softmin3m(u10, u20, A10) + fA0.y;                            \
    float A21 = softmin3m(u11, u21, A11) + fA1.y;                            \
    float B10 = softmin3m(curA0, A10, curB0) + fB0.x;                        \
    float B11 = softmin3m(curA1, A11, curB1) + fB1.x;                        \
    float B20 = softmin3m(A10, A20, B10) + fB0.y;                            \
    float B21 = softmin3m(A11, A21, B11) + fB1.y;                            \
    if ((T) == scap0)                                                        \
      capv0 = useB ? (useC2 ? B20 : B10) : (useC2 ? A20 : A10);              \
    if ((T) == scap1)                                                        \
      capv1 = useB ? (useC2 ? B21 : B11) : (useC2 ? A21 : A11);              \
    bool act0 = (PH1) ? (l + loff0 < (T)) : (l >= (T) - 64 + loff0);         \
    bool act1 = (PH1) ? (l + loff1 < (T)) : (l >= (T) - 64 + loff1);         \
    pub10 = act0 ? B10 : curB0;   pub11 = act1 ? B11 : curB1;                \
    curA0 = act0 ? A20 : curA0;   curA1 = act1 ? A21 : curA1;                \
    curB0 = act0 ? B20 : curB0;   curB1 = act1 ? B21 : curB1;                \
    diagA0 = u20;  diagA1 = u21;                                             \
    if (!(PH1)) {                                                            \
      wbase0[2 * (T) - 127] = B10;  wbase0[2 * (T) - 126] = B20;             \
      wbase1[2 * (T) - 127] = B11;  wbase1[2 * (T) - 126] = B21;             \
    }                                                                        \
  }

__global__ __launch_bounds__(128) void scan_kernel(
    const uint32* __restrict__ Dsk,
    const int* __restrict__ X_len, const int* __restrict__ Y_len,
    float* __restrict__ out)
{
    __shared__ __align__(16) float Frow[4][520];
    __shared__ float dumpArr[136];

    const int tid = threadIdx.x;
    const int l  = tid & 63;
    const int wu = __builtin_amdgcn_readfirstlane(tid >> 6);  // wave 0..1
    const int s0 = wu;          // pipeline-0 strip
    const int s1 = wu + 2;      // pipeline-1 strip
    const int bb = blockIdx.x;

    const int xl = X_len[bb], yl = Y_len[bb];
    const int wxl  = (xl - 1) >> 7;
    const int iw   = (xl - 1) & 127;
    const int lcap = iw >> 1;
    const int useB = iw & 1;
    const int Jcap = (yl - 1) >> 7;
    const int ycol = yl - (Jcap << 7);
    const int useC2 = 1 - (ycol & 1);
    const int tcap = ((ycol + 1) >> 1) + lcap;
    const int kmax = wxl + Jcap;              // <= 6

    const bool is63 = (l == 63);

    if (l == 0) { Frow[s0][0] = BIGC; Frow[s1][0] = BIGC; }
    __syncthreads();

    float curA0 = BIGC, curB0 = BIGC, pub10 = BIGC, diagA0 = BIGC, capv0 = 0.f;
    float curA1 = BIGC, curB1 = BIGC, pub11 = BIGC, diagA1 = BIGC, capv1 = 0.f;

    for (int k = 0; k <= kmax; ++k) {
        const int J0 = k - s0, J1 = k - s1;
        const bool t0 = (s0 <= wxl) && (J0 >= 0) && (J0 <= Jcap);
        const bool t1 = (s1 <= wxl) && (J1 >= 0) && (J1 <= Jcap);
        const int Jc0 = min(max(J0, 0), 3), Jc1 = min(max(J1, 0), 3);
        const int j00 = Jc0 << 7, j01 = Jc1 << 7;

        float Fodd0, Fev0, f00, Fodd1, Fev1, f01;
        if (s0 > 0) {
            Fodd0 = Frow[s0 - 1][j00 + 1 + 2 * l];
            Fev0  = Frow[s0 - 1][j00 + 2 + 2 * l];
            f00   = Frow[s0 - 1][j00];
        } else {
            Fodd0 = BIGC; Fev0 = BIGC;
            f00 = (J0 == 0) ? 0.0f : BIGC;
        }
        {
            Fodd1 = Frow[s1 - 1][j01 + 1 + 2 * l];
            Fev1  = Frow[s1 - 1][j01 + 2 + 2 * l];
            f01   = Frow[s1 - 1][j01];
        }
        diagA0 = (l == 0 && t0) ? f00 : diagA0;
        diagA1 = (l == 0 && t1) ? f01 : diagA1;

        const uint4* tp0 = (const uint4*)Dsk +
            ((((size_t)bb * 4 + s0) * 4) + Jc0) * 4096 + l;
        const uint4* tp1 = (const uint4*)Dsk +
            ((((size_t)bb * 4 + s1) * 4) + Jc1) * 4096 + l;
        const int scap0 = (t0 && s0 == wxl && J0 == Jcap) ? tcap : -1000;
        const int scap1 = (t1 && s1 == wxl && J1 == Jcap) ? tcap : -1000;
        float* wbase0 = (is63 && t0) ? (&Frow[s0][j00]) : (dumpArr + 4);
        float* wbase1 = (is63 && t1) ? (&Frow[s1][j01]) : (dumpArr + 4);
        const int loff0 = t0 ? 0 : 256;
        const int loff1 = t1 ? 0 : 256;

        uint4 dreg0[4], dreg1[4];
        dreg0[0] = tp0[0];   dreg0[1] = tp0[64];
        dreg0[2] = tp0[128]; dreg0[3] = tp0[192];
        dreg1[0] = tp1[0];   dreg1[1] = tp1[64];
        dreg1[2] = tp1[128]; dreg1[3] = tp1[192];

        // ---- phase 1: g 0..31 (t = 1..64) ----
#pragma unroll 1
        for (int m = 0; m < 8; ++m) {
#pragma unroll
            for (int q = 0; q < 4; ++q) {
                const int g = m * 4 + q;
                uint4 dc0 = dreg0[q];  dreg0[q] = tp0[(g + 4) * 64];
                uint4 dc1 = dreg1[q];  dreg1[q] = tp1[(g + 4) * 64];
                SS2(2 * g + 1, dc0.x, dc0.y, dc1.x, dc1.y, true)
                SS2(2 * g + 2, dc0.z, dc0.w, dc1.z, dc1.w, true)
            }
        }
        // t=64 boundary publish: lane63 cols 1,2
        wbase0[1] = pub10;  wbase0[2] = curB0;
        wbase1[1] = pub11;  wbase1[2] = curB1;

        // ---- phase 2: g 32..59 (t = 65..120) ----
#pragma unroll 1
        for (int m = 8; m < 15; ++m) {
#pragma unroll
            for (int q = 0; q < 4; ++q) {
                const int g = m * 4 + q;
                uint4 dc0 = dreg0[q];  dreg0[q] = tp0[(g + 4) * 64];
                uint4 dc1 = dreg1[q];  dreg1[q] = tp1[(g + 4) * 64];
                SS2(2 * g + 1, dc0.x, dc0.y, dc1.x, dc1.y, false)
                SS2(2 * g + 2, dc0.z, dc0.w, dc1.z, dc1.w, false)
            }
        }
        // ---- peel: g 60..63 (t = 121..127; t=128 skipped) ----
#pragma unroll
        for (int q = 0; q < 4; ++q) {
            const int g = 60 + q;
            uint4 dc0 = dreg0[q];
            uint4 dc1 = dreg1[q];
            SS2(2 * g + 1, dc0.x, dc0.y, dc1.x, dc1.y, false)
            if (g < 63) { SS2(2 * g + 2, dc0.z, dc0.w, dc1.z, dc1.w, false) }
        }
        __syncthreads();
    }

    if (s0 == wxl) {
        float o = rl(capv0, lcap);
        if (l == 0) out[bb] = o * LN2_F;
    }
    if (s1 == wxl) {
        float o = rl(capv1, lcap);
        if (l == 0) out[bb] = o * LN2_F;
    }
}

extern "C" void kernel_launch(void* const* d_in, const int* in_sizes, int n_in,
                              void* d_out, int out_size, void* d_ws, size_t ws_size,
                              hipStream_t stream)
{
    const float* X  = (const float*)d_in[0];
    const float* Y  = (const float*)d_in[1];
    const int*   xl = (const int*)d_in[2];
    const int*   yl = (const int*)d_in[3];
    float* out = (float*)d_out;
    uint32* Dsk = (uint32*)d_ws;   // 32 b * 4 strips * 4 J * 64 KB = 32 MB

    dist_kernel<<<dim3(4, 4, Bc), 256, 0, stream>>>(X, Y, Dsk);
    scan_kernel<<<Bc, 128, 0, stream>>>(Dsk, xl, yl, out);
}

// Round 10
// 214.847 us; speedup vs baseline: 1.4640x; 1.4640x over previous
//
#include <hip/hip_runtime.h>
#include <hip/hip_fp16.h>
#include <cstddef>

#define Bc   32
#define Nc   512
#define Mc   512
#define DFc  64
#define BIGC 1.0e10f
#define LOG2E_F 1.4426950408889634f
#define LN2_F   0.6931471805599453f
#define SQRT_LOG2E_F 1.2011224087864498f

typedef unsigned int uint32;

__device__ __forceinline__ float dpp_shr1(float oldv, float src) {
    return __int_as_float(__builtin_amdgcn_update_dpp(
        __float_as_int(oldv), __float_as_int(src), 0x138, 0xf, 0xf, false));
}
__device__ __forceinline__ float dpp_shr1_nc(float src) {
    return __int_as_float(__builtin_amdgcn_mov_dpp(
        __float_as_int(src), 0x138, 0xf, 0xf, false));
}
__device__ __forceinline__ float rl(float v, int lane) {
    return __int_as_float(__builtin_amdgcn_readlane(__float_as_int(v), lane));
}

// Bit-trick softmin, log2 domain, minus 127 (bias pre-folded into Dsk).
// No clamps: v_cvt_u32_f32 saturates negative inputs to 0 (= exp underflow).
__device__ __forceinline__ float softmin3m(float a, float b, float c) {
    float mn = fminf(fminf(a, b), c);
    float mx = fmaxf(fmaxf(a, b), c);
    float md = __builtin_amdgcn_fmed3f(a, b, c);
    uint32 b1 = (uint32)fmaf(mn - mx, 8388608.0f, 1065353216.0f);
    uint32 b2 = (uint32)fmaf(mn - md, 8388608.0f, 1065353216.0f);
    float E = 1.0f + (__int_as_float(b1) + __int_as_float(b2));
    return fmaf((float)__float_as_uint(E), -1.1920929e-7f, mn);
}

// ---------------------------------------------------------------------------
// Kernel 1 (unchanged from r8): scaled (x LOG2E, +127) fp16 distances,
// skewed dwordx4 layout for the 2-col superstep scan.
// ---------------------------------------------------------------------------
__global__ __launch_bounds__(256) void dist_kernel(
    const float* __restrict__ X, const float* __restrict__ Y,
    uint32* __restrict__ Dsk)
{
    __shared__ __align__(16) unsigned char SMEM[34816];
    unsigned short* XsH = (unsigned short*)SMEM;
    unsigned short* YsH = (unsigned short*)(SMEM + 16384);
    uint32* P = (uint32*)SMEM;

    const int b     = blockIdx.z;
    const int strip = blockIdx.y;
    const int J     = blockIdx.x;
    const int tid   = threadIdx.x;

    const float* Xg = X + ((size_t)b * Nc + strip * 128) * DFc;
    const float* Yg = Y + ((size_t)b * Mc + J * 128) * DFc;

#pragma unroll
    for (int it = 0; it < 8; ++it) {
        int e4 = it * 256 + tid;
        int n = e4 >> 4, k4 = (e4 & 15) * 4;
        float4 v = ((const float4*)Xg)[e4];
        __half2 h01 = __floats2half2_rn(v.x * SQRT_LOG2E_F, v.y * SQRT_LOG2E_F);
        __half2 h23 = __floats2half2_rn(v.z * SQRT_LOG2E_F, v.w * SQRT_LOG2E_F);
        int ho = (k4 + 8 * ((n >> 3) & 7)) & 63;
        uint2 u; u.x = *(uint32*)&h01; u.y = *(uint32*)&h23;
        *(uint2*)&XsH[n * 64 + ho] = u;
    }
#pragma unroll
    for (int it = 0; it < 8; ++it) {
        int e4 = it * 256 + tid;
        int m = e4 >> 4, k4 = (e4 & 15) * 4;
        float4 v = ((const float4*)Yg)[e4];
        __half2 h01 = __floats2half2_rn(v.x * SQRT_LOG2E_F, v.y * SQRT_LOG2E_F);
        __half2 h23 = __floats2half2_rn(v.z * SQRT_LOG2E_F, v.w * SQRT_LOG2E_F);
        int ho = (k4 + 8 * ((m >> 3) & 7)) & 63;
        uint2 u; u.x = *(uint32*)&h01; u.y = *(uint32*)&h23;
        *(uint2*)&YsH[m * 64 + ho] = u;
    }
    __syncthreads();

    const int tx = tid & 15;
    const int ty = tid >> 4;

    __half2 acc[8][8];
#pragma unroll
    for (int a = 0; a < 8; ++a)
#pragma unroll
        for (int c = 0; c < 8; ++c) acc[a][c] = __floats2half2_rn(0.f, 0.f);

    const int xrot = 8 * (ty & 7);
    const int yrot = 8 * (tx & 7);

#pragma unroll 2
    for (int k8 = 0; k8 < 8; ++k8) {
        uint4 xv[8], yvv[8];
#pragma unroll
        for (int a = 0; a < 8; ++a)
            xv[a] = *(const uint4*)&XsH[(8 * ty + a) * 64 + ((k8 * 8 + xrot) & 63)];
#pragma unroll
        for (int c = 0; c < 8; ++c)
            yvv[c] = *(const uint4*)&YsH[(8 * tx + c) * 64 + ((k8 * 8 + yrot) & 63)];
#pragma unroll
        for (int a = 0; a < 8; ++a) {
            const uint32 xa[4] = {xv[a].x, xv[a].y, xv[a].z, xv[a].w};
#pragma unroll
            for (int c = 0; c < 8; ++c) {
                const uint32 ya[4] = {yvv[c].x, yvv[c].y, yvv[c].z, yvv[c].w};
#pragma unroll
                for (int t = 0; t < 4; ++t) {
                    __half2 xd = *(const __half2*)&xa[t];
                    __half2 yd = *(const __half2*)&ya[t];
                    __half2 d = __hsub2(xd, yd);
                    acc[a][c] = __hfma2(d, d, acc[a][c]);
                }
            }
        }
    }
    __syncthreads();

#pragma unroll
    for (int a = 0; a < 8; a += 2) {
        int p = 4 * ty + (a >> 1);
#pragma unroll
        for (int c = 0; c < 8; ++c) {
            float2 fa = __half22float2(acc[a][c]);
            float2 fb = __half22float2(acc[a + 1][c]);
            __half2 h = __floats2half2_rn(fa.x + fa.y + 127.0f,
                                          fb.x + fb.y + 127.0f);
            P[(8 * tx + c) * 67 + p] = *(uint32*)&h;
        }
    }
    __syncthreads();

    const int l = tid & 63;
    const int q = tid >> 6;
    uint4* outt = (uint4*)Dsk + (((size_t)b * 4 + strip) * 4 + J) * 4096;
    const uint32* Pl = P + l;
#pragma unroll
    for (int gi = 0; gi < 16; ++gi) {
        int g = q + 4 * gi;
        int ka = 4 * g - 2 * l;
        int c0 = min(max(ka,     0), 127);
        int c1 = min(max(ka + 1, 0), 127);
        int c2 = min(max(ka + 2, 0), 127);
        int c3 = min(max(ka + 3, 0), 127);
        uint32 p0 = Pl[c0 * 67];
        uint32 p1 = Pl[c1 * 67];
        uint32 p2 = Pl[c2 * 67];
        uint32 p3 = Pl[c3 * 67];
        uint4 v;
        v.x = (p0 & 0xffffu) | (p1 << 16);
        v.y = (p0 >> 16)     | (p1 & 0xffff0000u);
        v.z = (p2 & 0xffffu) | (p3 << 16);
        v.w = (p2 >> 16)     | (p3 & 0xffff0000u);
        outt[g * 64 + l] = v;
    }
}

// ---------------------------------------------------------------------------
// Kernel 2: single-pipeline 2-col superstep scan (r8 structure) with the
// issue-law trims: scalar (SALU-branch) output capture, clamp-free softmin,
// uniform-base global prefetch addressing. 4 waves (1/SIMD), 32 blocks.
// ---------------------------------------------------------------------------
#define SSTEP(T, dAw, dBw, PH1)                                            \
  {                                                                        \
    float2 fA = __half22float2(*(const __half2*)&(dAw));                   \
    float2 fB = __half22float2(*(const __half2*)&(dBw));                   \
    float u1, u2;                                                          \
    if (PH1) {                                                             \
      u1 = dpp_shr1(rl(Fodd, (T) - 1), pub1);                              \
      u2 = dpp_shr1(rl(Fev,  (T) - 1), curB);                              \
    } else {                                                               \
      u1 = dpp_shr1_nc(pub1);                                              \
      u2 = dpp_shr1_nc(curB);                                              \
    }                                                                      \
    float A1 = softmin3m(diagA, u1, curA) + fA.x;                          \
    float A2 = softmin3m(u1, u2, A1) + fA.y;                               \
    float B1 = softmin3m(curA, A1, curB) + fB.x;                           \
    float B2 = softmin3m(A1, A2, B1) + fB.y;                               \
    if ((T) == scap)                                                       \
      capv = useB ? (useC2 ? B2 : B1) : (useC2 ? A2 : A1);                 \
    bool act = (PH1) ? (l < (T)) : (l >= (T) - 64);                        \
    pub1  = act ? B1 : curB;   /* reads curB BEFORE update */              \
    curA  = act ? A2 : curA;                                               \
    curB  = act ? B2 : curB;                                               \
    diagA = u2;                                                            \
    if (!(PH1)) { wbase[2 * (T) - 127] = B1; wbase[2 * (T) - 126] = B2; }  \
  }

__global__ __launch_bounds__(256) void scan_kernel(
    const uint32* __restrict__ Dsk,
    const int* __restrict__ X_len, const int* __restrict__ Y_len,
    float* __restrict__ out)
{
    __shared__ __align__(16) float Frow[4][520];
    __shared__ float dumpArr[136];

    const int tid = threadIdx.x;
    const int l  = tid & 63;
    const int wl = __builtin_amdgcn_readfirstlane(tid >> 6);  // strip 0..3
    const int bb = blockIdx.x;

    const int xl = X_len[bb], yl = Y_len[bb];
    const int wxl  = (xl - 1) >> 7;           // capture strip
    const int iw   = (xl - 1) & 127;
    const int lcap = iw >> 1;                 // capture lane
    const int useB = iw & 1;                  // row parity (A/B)
    const int Jcap = (yl - 1) >> 7;           // capture tile (128-col)
    const int ycol = yl - (Jcap << 7);        // 1..128
    const int useC2 = 1 - (ycol & 1);         // even rel-col -> second cell
    const int tcap = ((ycol + 1) >> 1) + lcap;   // in [1,127]
    const int kmax = wxl + Jcap;              // <= 6

    const bool is63 = (l == 63);

    if (l == 0) Frow[wl][0] = BIGC;           // col-0 border for f0 at J=0
    __syncthreads();

    float curA = BIGC, curB = BIGC, pub1 = BIGC;
    float diagA = BIGC;
    float capv = 0.0f;

    for (int k = 0; k <= kmax; ++k) {
        int J = k - wl;
        if (wl <= wxl && 0 <= J && J <= Jcap) {
            const int j0 = J << 7;
            float Fodd, Fev, f0;
            if (wl > 0) {
                Fodd = Frow[wl - 1][j0 + 1 + 2 * l];   // odd rel-cols 1..127
                Fev  = Frow[wl - 1][j0 + 2 + 2 * l];   // even rel-cols 2..128
                f0   = Frow[wl - 1][j0];               // diag seed col j0
            } else {
                Fodd = BIGC; Fev = BIGC;
                f0 = (J == 0) ? 0.0f : BIGC;           // R[0][0] = 0
            }
            diagA = (l == 0) ? f0 : diagA;

            // uniform byte base + per-lane 16B offset: keeps prefetch
            // address bumps on SALU (imm/uniform), off the VALU budget.
            const char* tb = (const char*)Dsk +
                (((((size_t)bb * 4 + wl) * 4) + J) * 4096) * 16;
            const int voff = l * 16;
            const int scap = (wl == wxl && J == Jcap) ? tcap : -1000;
            float* wbase = is63 ? (&Frow[wl][j0]) : (dumpArr + 4);

            uint4 dreg[4];
            dreg[0] = *(const uint4*)(tb + voff);
            dreg[1] = *(const uint4*)(tb + voff + 1024);
            dreg[2] = *(const uint4*)(tb + voff + 2048);
            dreg[3] = *(const uint4*)(tb + voff + 3072);

            // ---- phase 1: g 0..31 (t = 1..64): lane0 inject, no stores ----
#pragma unroll 1
            for (int m = 0; m < 8; ++m) {
#pragma unroll
                for (int q = 0; q < 4; ++q) {
                    const int g = m * 4 + q;
                    uint4 dc = dreg[q];
                    dreg[q] = *(const uint4*)(tb + voff + (g + 4) * 1024);
                    SSTEP(2 * g + 1, dc.x, dc.y, true)
                    SSTEP(2 * g + 2, dc.z, dc.w, true)
                }
            }
            // t=64 boundary publish: lane63 (just activated) cols 1,2
            wbase[1] = pub1;
            wbase[2] = curB;

            // ---- phase 2: g 32..59 (t = 65..120): no inject, store pair ----
#pragma unroll 1
            for (int m = 8; m < 15; ++m) {
#pragma unroll
                for (int q = 0; q < 4; ++q) {
                    const int g = m * 4 + q;
                    uint4 dc = dreg[q];
                    dreg[q] = *(const uint4*)(tb + voff + (g + 4) * 1024);
                    SSTEP(2 * g + 1, dc.x, dc.y, false)
                    SSTEP(2 * g + 2, dc.z, dc.w, false)
                }
            }
            // ---- peel: g 60..63 (t = 121..127; t=128 skipped) ----
#pragma unroll
            for (int q = 0; q < 4; ++q) {
                const int g = 60 + q;
                uint4 dc = dreg[q];
                SSTEP(2 * g + 1, dc.x, dc.y, false)
                if (g < 63) { SSTEP(2 * g + 2, dc.z, dc.w, false) }
            }
        }
        __syncthreads();
    }

    if (wl == wxl) {
        float o = rl(capv, lcap);
        if (l == 0) out[bb] = o * LN2_F;
    }
}

extern "C" void kernel_launch(void* const* d_in, const int* in_sizes, int n_in,
                              void* d_out, int out_size, void* d_ws, size_t ws_size,
                              hipStream_t stream)
{
    const float* X  = (const float*)d_in[0];
    const float* Y  = (const float*)d_in[1];
    const int*   xl = (const int*)d_in[2];
    const int*   yl = (const int*)d_in[3];
    float* out = (float*)d_out;
    uint32* Dsk = (uint32*)d_ws;   // 32 b * 4 strips * 4 J * 64 KB = 32 MB

    dist_kernel<<<dim3(4, 4, Bc), 256, 0, stream>>>(X, Y, Dsk);
    scan_kernel<<<Bc, 256, 0, stream>>>(Dsk, xl, yl, out);
}